// Round 1
// baseline (101.812 us; speedup 1.0000x reference)
//
#include <hip/hip_runtime.h>

#define NGRID 257
#define LDS_PITCH 260                      // halfs per row; 520 B stride (multiple of 8)
#define TABLE_ELEMS (NGRID * NGRID)        // 66049
#define LDS_BYTES (LDS_PITCH * NGRID * 2)  // 133640 B < 160 KiB

typedef _Float16 half4_t __attribute__((ext_vector_type(4)));

__device__ __forceinline__ void lag_basis(float t, float b[5]) {
    // L_j(t) = prod_{k != j} (t - k) / (j - k), nodes 0..4
    float f0 = t;
    float f1 = t - 1.0f;
    float f2 = t - 2.0f;
    float f3 = t - 3.0f;
    float f4 = t - 4.0f;
    float p01 = f0 * f1;
    float p12 = f1 * f2;
    float p23 = f2 * f3;
    float p34 = f3 * f4;
    b[0] = p12 * p34 * (1.0f / 24.0f);        // (t-1)(t-2)(t-3)(t-4)/24
    b[1] = f0 * f2 * p34 * (-1.0f / 6.0f);    // t(t-2)(t-3)(t-4)/-6
    b[2] = p01 * p34 * (1.0f / 4.0f);         // t(t-1)(t-3)(t-4)/4
    b[3] = p01 * f2 * f4 * (-1.0f / 6.0f);    // t(t-1)(t-2)(t-4)/-6
    b[4] = p01 * p23 * (1.0f / 24.0f);        // t(t-1)(t-2)(t-3)/24
}

__device__ __forceinline__ float eval_pt(const _Float16* __restrict__ lds,
                                         float x0, float x1) {
    float u0 = x0 * 64.0f;
    float u1 = x1 * 64.0f;
    float c0 = fminf(fmaxf(floorf(u0), 0.0f), 63.0f);
    float c1 = fminf(fmaxf(floorf(u1), 0.0f), 63.0f);
    float t0 = (u0 - c0) * 4.0f;
    float t1 = (u1 - c1) * 4.0f;
    float b0[5], b1[5];
    lag_basis(t0, b0);
    lag_basis(t1, b1);
    // row index from coord 0, col index from coord 1 (matches reference einsum)
    int off = ((int)c0 * 4) * LDS_PITCH + ((int)c1 * 4);
    float acc = 0.0f;
#pragma unroll
    for (int i = 0; i < 5; ++i) {
        const _Float16* rowp = lds + off + i * LDS_PITCH;
        half4_t h4 = *(const half4_t*)rowp;   // cols 0..3 (8B-aligned: 520B rows, 8B col base)
        float e4 = (float)rowp[4];            // col 4
        float rd = (float)h4[0] * b1[0];
        rd = fmaf((float)h4[1], b1[1], rd);
        rd = fmaf((float)h4[2], b1[2], rd);
        rd = fmaf((float)h4[3], b1[3], rd);
        rd = fmaf(e4, b1[4], rd);
        acc = fmaf(b0[i], rd, acc);
    }
    return acc;
}

__launch_bounds__(1024, 4)
__global__ void lagrange_kernel(const float* __restrict__ inputs,
                                const float* __restrict__ coe,
                                float* __restrict__ out,
                                int npairs) {
    extern __shared__ _Float16 lds[];
    // Stage + convert the full 257x257 f32 table into LDS as f16 (row pitch 260)
    for (int e = threadIdx.x; e < TABLE_ELEMS; e += blockDim.x) {
        int r = e / NGRID;
        int c = e - r * NGRID;
        lds[r * LDS_PITCH + c] = (_Float16)coe[e];
    }
    __syncthreads();

    const float4* __restrict__ in4 = (const float4*)inputs;  // 2 points per float4
    float2* __restrict__ out2 = (float2*)out;
    int stride = gridDim.x * blockDim.x;
    for (int p = blockIdx.x * blockDim.x + threadIdx.x; p < npairs; p += stride) {
        float4 v = in4[p];
        float2 r;
        r.x = eval_pt(lds, v.x, v.y);
        r.y = eval_pt(lds, v.z, v.w);
        out2[p] = r;
    }
}

extern "C" void kernel_launch(void* const* d_in, const int* in_sizes, int n_in,
                              void* d_out, int out_size, void* d_ws, size_t ws_size,
                              hipStream_t stream) {
    const float* inputs = (const float*)d_in[0];   // (2048,2048,2) f32
    const float* coe    = (const float*)d_in[1];   // (257,257) f32
    float* out = (float*)d_out;                    // (2048,2048) f32
    int npts = out_size;                           // 4,194,304
    int npairs = npts >> 1;

    // >64 KiB dynamic LDS needs the attribute; host-side state change only,
    // idempotent and graph-capture-safe.
    (void)hipFuncSetAttribute((const void*)lagrange_kernel,
                              hipFuncAttributeMaxDynamicSharedMemorySize,
                              LDS_BYTES);

    dim3 grid(256), block(1024);   // 1 block/CU (LDS-limited), 16 waves/block
    hipLaunchKernelGGL(lagrange_kernel, grid, block, LDS_BYTES, stream,
                       inputs, coe, out, npairs);
}

// Round 2
// 100.392 us; speedup vs baseline: 1.0141x; 1.0141x over previous
//
#include <hip/hip_runtime.h>

#define NGRID 257
#define LDS_PITCH 260                      // halfs per row; 520 B stride (multiple of 8)
#define LDS_BYTES (LDS_PITCH * NGRID * 2)  // 133640 B < 160 KiB
#define BLOCK 1024
#define GRID 256
#define ITERS 8                            // 2,097,152 pairs / (256*1024) threads

typedef _Float16 half4_t __attribute__((ext_vector_type(4)));

// 4-byte-aligned float4 view (coe rows have odd stride 257)
struct __attribute__((packed, aligned(4))) f4u { float x, y, z, w; };

__device__ __forceinline__ void lag_basis(float t, float b[5]) {
    // L_j(t) = prod_{k != j} (t - k) / (j - k), nodes 0..4
    float f0 = t;
    float f1 = t - 1.0f;
    float f2 = t - 2.0f;
    float f3 = t - 3.0f;
    float f4 = t - 4.0f;
    float p01 = f0 * f1;
    float p12 = f1 * f2;
    float p23 = f2 * f3;
    float p34 = f3 * f4;
    b[0] = p12 * p34 * (1.0f / 24.0f);
    b[1] = f0 * f2 * p34 * (-1.0f / 6.0f);
    b[2] = p01 * p34 * (1.0f / 4.0f);
    b[3] = p01 * f2 * f4 * (-1.0f / 6.0f);
    b[4] = p01 * p23 * (1.0f / 24.0f);
}

// Evaluate two points (v.xy and v.zw) with interleaved LDS reads.
__device__ __forceinline__ float2 eval_pair(const _Float16* __restrict__ lds,
                                            float4 v) {
    // --- index + basis for both points (pure VALU, no memory) ---
    float uA0 = v.x * 64.0f, uA1 = v.y * 64.0f;
    float uB0 = v.z * 64.0f, uB1 = v.w * 64.0f;
    float cA0 = fminf(fmaxf(floorf(uA0), 0.0f), 63.0f);
    float cA1 = fminf(fmaxf(floorf(uA1), 0.0f), 63.0f);
    float cB0 = fminf(fmaxf(floorf(uB0), 0.0f), 63.0f);
    float cB1 = fminf(fmaxf(floorf(uB1), 0.0f), 63.0f);
    float bA0[5], bA1[5], bB0[5], bB1[5];
    lag_basis((uA0 - cA0) * 4.0f, bA0);
    lag_basis((uA1 - cA1) * 4.0f, bA1);
    lag_basis((uB0 - cB0) * 4.0f, bB0);
    lag_basis((uB1 - cB1) * 4.0f, bB1);
    int offA = ((int)cA0 * 4) * LDS_PITCH + ((int)cA1 * 4);
    int offB = ((int)cB0 * 4) * LDS_PITCH + ((int)cB1 * 4);

    // --- issue all 20 LDS reads first, then do the math ---
    half4_t hA[5], hB[5];
    _Float16 eA[5], eB[5];
#pragma unroll
    for (int i = 0; i < 5; ++i) {
        const _Float16* rA = lds + offA + i * LDS_PITCH;
        const _Float16* rB = lds + offB + i * LDS_PITCH;
        hA[i] = *(const half4_t*)rA;   // 8B-aligned (520B rows, 8B col base)
        hB[i] = *(const half4_t*)rB;
        eA[i] = rA[4];
        eB[i] = rB[4];
    }

    float accA = 0.0f, accB = 0.0f;
#pragma unroll
    for (int i = 0; i < 5; ++i) {
        float rdA = (float)hA[i][0] * bA1[0];
        rdA = fmaf((float)hA[i][1], bA1[1], rdA);
        rdA = fmaf((float)hA[i][2], bA1[2], rdA);
        rdA = fmaf((float)hA[i][3], bA1[3], rdA);
        rdA = fmaf((float)eA[i], bA1[4], rdA);
        accA = fmaf(bA0[i], rdA, accA);
        float rdB = (float)hB[i][0] * bB1[0];
        rdB = fmaf((float)hB[i][1], bB1[1], rdB);
        rdB = fmaf((float)hB[i][2], bB1[2], rdB);
        rdB = fmaf((float)hB[i][3], bB1[3], rdB);
        rdB = fmaf((float)eB[i], bB1[4], rdB);
        accB = fmaf(bB0[i], rdB, accB);
    }
    return make_float2(accA, accB);
}

__launch_bounds__(BLOCK)
__global__ void lagrange_kernel(const float* __restrict__ inputs,
                                const float* __restrict__ coe,
                                float* __restrict__ out,
                                int npairs) {
    extern __shared__ _Float16 lds[];

    // --- staged table load: float4 (4B-aligned) -> half4 ds_write_b64 ---
    // 257 rows x 65 quad-groups (last group is the single col-256 element)
    for (int g = threadIdx.x; g < NGRID * 65; g += BLOCK) {
        int r = g / 65;                 // constant divisor -> magic mul
        int c4 = (g - r * 65) * 4;
        if (c4 < 256) {
            f4u q = *(const f4u*)(coe + r * NGRID + c4);
            half4_t h = { (_Float16)q.x, (_Float16)q.y,
                          (_Float16)q.z, (_Float16)q.w };
            *(half4_t*)(lds + r * LDS_PITCH + c4) = h;
        } else {
            lds[r * LDS_PITCH + 256] = (_Float16)coe[r * NGRID + 256];
        }
    }
    __syncthreads();

    const float4* __restrict__ in4 = (const float4*)inputs;  // 2 points / float4
    float2* __restrict__ out2 = (float2*)out;
    const int tid = blockIdx.x * BLOCK + threadIdx.x;
    const int stride = GRID * BLOCK;

    // hoist all 8 input loads: 8 independent VMEM ops in flight, latency paid once
    float4 v[ITERS];
#pragma unroll
    for (int k = 0; k < ITERS; ++k) {
        int p = tid + k * stride;
        if (p < npairs) v[k] = in4[p];
    }
#pragma unroll
    for (int k = 0; k < ITERS; ++k) {
        int p = tid + k * stride;
        if (p < npairs) out2[p] = eval_pair(lds, v[k]);
    }
}

extern "C" void kernel_launch(void* const* d_in, const int* in_sizes, int n_in,
                              void* d_out, int out_size, void* d_ws, size_t ws_size,
                              hipStream_t stream) {
    const float* inputs = (const float*)d_in[0];   // (2048,2048,2) f32
    const float* coe    = (const float*)d_in[1];   // (257,257) f32
    float* out = (float*)d_out;                    // (2048,2048) f32
    int npairs = out_size >> 1;                    // 2,097,152

    // >64 KiB dynamic LDS needs the attribute; host-side, idempotent,
    // graph-capture-safe.
    (void)hipFuncSetAttribute((const void*)lagrange_kernel,
                              hipFuncAttributeMaxDynamicSharedMemorySize,
                              LDS_BYTES);

    dim3 grid(GRID), block(BLOCK);   // 1 block/CU (LDS-limited), 16 waves/CU
    hipLaunchKernelGGL(lagrange_kernel, grid, block, LDS_BYTES, stream,
                       inputs, coe, out, npairs);
}

// Round 4
// 95.693 us; speedup vs baseline: 1.0639x; 1.0491x over previous
//
#include <hip/hip_runtime.h>

#define NGRID 257
#define LDS_PITCH 260                      // halfs per row; 520 B stride (multiple of 8)
#define LDS_BYTES (LDS_PITCH * NGRID * 2)  // 133640 B < 160 KiB
#define BLOCK 1024
#define GRID 256
#define ITERS 8                            // 2,097,152 pairs == GRID*BLOCK*ITERS exactly

typedef _Float16 half2_t __attribute__((ext_vector_type(2)));
typedef _Float16 half4_t __attribute__((ext_vector_type(4)));
typedef float    f2v     __attribute__((ext_vector_type(2)));  // native vec for nt-store

// 4-byte-aligned float4 view (coe rows have odd stride 257)
struct __attribute__((packed, aligned(4))) f4u { float x, y, z, w; };

// Raw LDS fragments for one pair of points (A = v.xy, B = v.zw)
struct Frag {
    half4_t hA[5], hB[5];
    _Float16 eA[5], eB[5];
};

__device__ __forceinline__ void lag_basis(float t, float b[5]) {
    float f0 = t;
    float f1 = t - 1.0f;
    float f2 = t - 2.0f;
    float f3 = t - 3.0f;
    float f4 = t - 4.0f;
    float p01 = f0 * f1;
    float p12 = f1 * f2;
    float p23 = f2 * f3;
    float p34 = f3 * f4;
    b[0] = p12 * p34 * (1.0f / 24.0f);
    b[1] = f0 * f2 * p34 * (-1.0f / 6.0f);
    b[2] = p01 * p34 * (1.0f / 4.0f);
    b[3] = p01 * f2 * f4 * (-1.0f / 6.0f);
    b[4] = p01 * p23 * (1.0f / 24.0f);
}

__device__ __forceinline__ int pt_off(float x0, float x1) {
    float u0 = x0 * 64.0f, u1 = x1 * 64.0f;
    float c0 = fminf(fmaxf(floorf(u0), 0.0f), 63.0f);
    float c1 = fminf(fmaxf(floorf(u1), 0.0f), 63.0f);
    return ((int)c0 * 4) * LDS_PITCH + ((int)c1 * 4);
}

// Issue all 20 LDS reads for a pair (no math on the results here).
__device__ __forceinline__ void stage_issue(const _Float16* __restrict__ lds,
                                            float4 v, Frag& f) {
    int offA = pt_off(v.x, v.y);
    int offB = pt_off(v.z, v.w);
#pragma unroll
    for (int i = 0; i < 5; ++i) {
        const _Float16* rA = lds + offA + i * LDS_PITCH;
        const _Float16* rB = lds + offB + i * LDS_PITCH;
        f.hA[i] = *(const half4_t*)rA;   // 8B-aligned (520B rows, 8B col base)
        f.hB[i] = *(const half4_t*)rB;
        f.eA[i] = rA[4];
        f.eB[i] = rB[4];
    }
}

// Consume one point's fragments. Recomputes basis from v (pure VALU,
// fills the LDS-latency window; cheaper than carrying t in the state).
__device__ __forceinline__ float eval_from(const half4_t (&h)[5],
                                           const _Float16 (&e)[5],
                                           float x0, float x1) {
    float u0 = x0 * 64.0f, u1 = x1 * 64.0f;
    float c0 = fminf(fmaxf(floorf(u0), 0.0f), 63.0f);
    float c1 = fminf(fmaxf(floorf(u1), 0.0f), 63.0f);
    float b0[5], b1[5];
    lag_basis((u0 - c0) * 4.0f, b0);
    lag_basis((u1 - c1) * 4.0f, b1);
    float acc = 0.0f;
#if __has_builtin(__builtin_amdgcn_fdot2)
    half2_t b01 = { (_Float16)b1[0], (_Float16)b1[1] };
    half2_t b23 = { (_Float16)b1[2], (_Float16)b1[3] };
#pragma unroll
    for (int i = 0; i < 5; ++i) {
        half2_t lo = __builtin_shufflevector(h[i], h[i], 0, 1);
        half2_t hi = __builtin_shufflevector(h[i], h[i], 2, 3);
        float rd = (float)e[i] * b1[4];
        rd = __builtin_amdgcn_fdot2(hi, b23, rd, false);
        rd = __builtin_amdgcn_fdot2(lo, b01, rd, false);
        acc = fmaf(b0[i], rd, acc);
    }
#else
#pragma unroll
    for (int i = 0; i < 5; ++i) {
        float rd = (float)h[i][0] * b1[0];
        rd = fmaf((float)h[i][1], b1[1], rd);
        rd = fmaf((float)h[i][2], b1[2], rd);
        rd = fmaf((float)h[i][3], b1[3], rd);
        rd = fmaf((float)e[i], b1[4], rd);
        acc = fmaf(b0[i], rd, acc);
    }
#endif
    return acc;
}

__launch_bounds__(BLOCK, 4)   // force VGPR<=128 so we keep 16 waves/CU
__global__ void lagrange_kernel(const float* __restrict__ inputs,
                                const float* __restrict__ coe,
                                float* __restrict__ out,
                                int npairs) {
    extern __shared__ _Float16 lds[];

    // --- staged table load: float4 (4B-aligned) -> half4 ds_write_b64 ---
    for (int g = threadIdx.x; g < NGRID * 65; g += BLOCK) {
        int r = g / 65;                 // constant divisor -> magic mul
        int c4 = (g - r * 65) * 4;
        if (c4 < 256) {
            f4u q = *(const f4u*)(coe + r * NGRID + c4);
            half4_t h = { (_Float16)q.x, (_Float16)q.y,
                          (_Float16)q.z, (_Float16)q.w };
            *(half4_t*)(lds + r * LDS_PITCH + c4) = h;
        } else {
            lds[r * LDS_PITCH + 256] = (_Float16)coe[r * NGRID + 256];
        }
    }
    __syncthreads();

    const float4* __restrict__ in4 = (const float4*)inputs;  // 2 points / float4
    f2v* __restrict__ out2 = (f2v*)out;
    const int tid = blockIdx.x * BLOCK + threadIdx.x;
    const int stride = GRID * BLOCK;
    // npairs == GRID*BLOCK*ITERS exactly (2,097,152) -> no bounds checks
    (void)npairs;

    // --- software pipeline: depth-2 input prefetch, depth-1 LDS prefetch ---
    float4 v[ITERS];        // rolling live range (~3 in flight)
    Frag frag[2];

    v[0] = in4[tid];
    v[1] = in4[tid + stride];
    stage_issue(lds, v[0], frag[0]);

#pragma unroll
    for (int k = 0; k < ITERS; ++k) {
        if (k + 2 < ITERS) v[k + 2] = in4[tid + (k + 2) * stride];
        if (k + 1 < ITERS) stage_issue(lds, v[k + 1], frag[(k + 1) & 1]);
        const Frag& f = frag[k & 1];
        f2v r;
        r.x = eval_from(f.hA, f.eA, v[k].x, v[k].y);
        r.y = eval_from(f.hB, f.eB, v[k].z, v[k].w);
        __builtin_nontemporal_store(r, &out2[tid + k * stride]);
    }
}

extern "C" void kernel_launch(void* const* d_in, const int* in_sizes, int n_in,
                              void* d_out, int out_size, void* d_ws, size_t ws_size,
                              hipStream_t stream) {
    const float* inputs = (const float*)d_in[0];   // (2048,2048,2) f32
    const float* coe    = (const float*)d_in[1];   // (257,257) f32
    float* out = (float*)d_out;                    // (2048,2048) f32
    int npairs = out_size >> 1;                    // 2,097,152

    (void)hipFuncSetAttribute((const void*)lagrange_kernel,
                              hipFuncAttributeMaxDynamicSharedMemorySize,
                              LDS_BYTES);

    dim3 grid(GRID), block(BLOCK);   // 1 block/CU (LDS-limited), 16 waves/CU
    hipLaunchKernelGGL(lagrange_kernel, grid, block, LDS_BYTES, stream,
                       inputs, coe, out, npairs);
}

// Round 5
// 94.872 us; speedup vs baseline: 1.0732x; 1.0087x over previous
//
#include <hip/hip_runtime.h>

#define NGRID 257
#define LDS_PITCH 260                      // halfs per row; 520 B stride (65*8B / 130*4B)
#define LDS_BYTES (LDS_PITCH * NGRID * 2)  // 133640 B < 160 KiB
#define BLOCK 1024
#define GRID 256
#define ITERS 8                            // 2,097,152 pairs == GRID*BLOCK*ITERS exactly

typedef _Float16 half2_t __attribute__((ext_vector_type(2)));
typedef _Float16 half4_t __attribute__((ext_vector_type(4)));
typedef float    f2v     __attribute__((ext_vector_type(2)));  // native vec for nt-store

// 4-byte-aligned float4 view (coe rows have odd stride 257)
struct __attribute__((packed, aligned(4))) f4u { float x, y, z, w; };

// Raw LDS fragments for one point: 5 rows x (cols0-3 as half4, cols4-5 as half2)
struct PtFrag {
    half4_t m[5];
    half2_t t[5];
};

__device__ __forceinline__ void lag_basis(float t, float b[5]) {
    float f0 = t;
    float f1 = t - 1.0f;
    float f2 = t - 2.0f;
    float f3 = t - 3.0f;
    float f4 = t - 4.0f;
    float p01 = f0 * f1;
    float p12 = f1 * f2;
    float p23 = f2 * f3;
    float p34 = f3 * f4;
    b[0] = p12 * p34 * (1.0f / 24.0f);
    b[1] = f0 * f2 * p34 * (-1.0f / 6.0f);
    b[2] = p01 * p34 * (1.0f / 4.0f);
    b[3] = p01 * f2 * f4 * (-1.0f / 6.0f);
    b[4] = p01 * p23 * (1.0f / 24.0f);
}

__device__ __forceinline__ int pt_off(float x0, float x1) {
    float u0 = x0 * 64.0f, u1 = x1 * 64.0f;
    float c0 = fminf(fmaxf(floorf(u0), 0.0f), 63.0f);
    float c1 = fminf(fmaxf(floorf(u1), 0.0f), 63.0f);
    return ((int)c0 * 4) * LDS_PITCH + ((int)c1 * 4);
}

// Issue all 10 LDS reads for one point; size-adjacent ordering so the DS
// combiner can fuse row pairs into ds_read2_b64 / ds_read2_b32.
__device__ __forceinline__ void stage_point(const _Float16* __restrict__ lds,
                                            int off, PtFrag& f) {
    const _Float16* base = lds + off;
#pragma unroll
    for (int i = 0; i < 5; ++i)
        f.m[i] = *(const half4_t*)(base + i * LDS_PITCH);       // 8B-aligned
#pragma unroll
    for (int i = 0; i < 5; ++i)
        f.t[i] = *(const half2_t*)(base + i * LDS_PITCH + 4);   // 4B-aligned
}

// Consume one point's fragments; recomputes basis (pure VALU).
__device__ __forceinline__ float eval_pt(const PtFrag& f, float x0, float x1) {
    float u0 = x0 * 64.0f, u1 = x1 * 64.0f;
    float c0 = fminf(fmaxf(floorf(u0), 0.0f), 63.0f);
    float c1 = fminf(fmaxf(floorf(u1), 0.0f), 63.0f);
    float b0[5], b1[5];
    lag_basis((u0 - c0) * 4.0f, b0);
    lag_basis((u1 - c1) * 4.0f, b1);
    float acc = 0.0f;
#if __has_builtin(__builtin_amdgcn_fdot2)
    half2_t b01 = { (_Float16)b1[0], (_Float16)b1[1] };
    half2_t b23 = { (_Float16)b1[2], (_Float16)b1[3] };
#pragma unroll
    for (int i = 0; i < 5; ++i) {
        half2_t lo = __builtin_shufflevector(f.m[i], f.m[i], 0, 1);
        half2_t hi = __builtin_shufflevector(f.m[i], f.m[i], 2, 3);
        float rd = (float)f.t[i][0] * b1[4];
        rd = __builtin_amdgcn_fdot2(hi, b23, rd, false);
        rd = __builtin_amdgcn_fdot2(lo, b01, rd, false);
        acc = fmaf(b0[i], rd, acc);
    }
#else
#pragma unroll
    for (int i = 0; i < 5; ++i) {
        float rd = (float)f.m[i][0] * b1[0];
        rd = fmaf((float)f.m[i][1], b1[1], rd);
        rd = fmaf((float)f.m[i][2], b1[2], rd);
        rd = fmaf((float)f.m[i][3], b1[3], rd);
        rd = fmaf((float)f.t[i][0], b1[4], rd);
        acc = fmaf(b0[i], rd, acc);
    }
#endif
    return acc;
}

__launch_bounds__(BLOCK, 4)   // VGPR<=128 so the single 133KB-LDS block keeps 16 waves/CU
__global__ void lagrange_kernel(const float* __restrict__ inputs,
                                const float* __restrict__ coe,
                                float* __restrict__ out,
                                int npairs) {
    extern __shared__ _Float16 lds[];

    // --- staged table load: float4 (4B-aligned) -> half4 ds_write_b64 ---
    for (int g = threadIdx.x; g < NGRID * 65; g += BLOCK) {
        int r = g / 65;                 // constant divisor -> magic mul
        int c4 = (g - r * 65) * 4;
        if (c4 < 256) {
            f4u q = *(const f4u*)(coe + r * NGRID + c4);
            half4_t h = { (_Float16)q.x, (_Float16)q.y,
                          (_Float16)q.z, (_Float16)q.w };
            *(half4_t*)(lds + r * LDS_PITCH + c4) = h;
        } else {
            lds[r * LDS_PITCH + 256] = (_Float16)coe[r * NGRID + 256];
        }
    }
    __syncthreads();

    const float4* __restrict__ in4 = (const float4*)inputs;  // 2 points / float4
    f2v* __restrict__ out2 = (f2v*)out;
    const int tid = blockIdx.x * BLOCK + threadIdx.x;
    const int stride = GRID * BLOCK;
    (void)npairs;  // npairs == GRID*BLOCK*ITERS exactly -> no bounds checks

    // --- explicit 2-phase software pipeline, pinned with sched_barrier(0) ---
    float4 va, vb, vc;      // rolling input window (current / next / next2)
    PtFrag fA[2], fB[2];    // double-buffered fragments for points A and B

    va = in4[tid];
    vb = in4[tid + stride];
    stage_point(lds, pt_off(va.x, va.y), fA[0]);
    stage_point(lds, pt_off(va.z, va.w), fB[0]);

#pragma unroll
    for (int k = 0; k < ITERS; ++k) {
        // ---- phase A: prefetch input k+2, issue LDS reads for pair k+1 ----
        if (k + 2 < ITERS) vc = in4[tid + (k + 2) * stride];
        if (k + 1 < ITERS) {
            stage_point(lds, pt_off(vb.x, vb.y), fA[(k + 1) & 1]);
            stage_point(lds, pt_off(vb.z, vb.w), fB[(k + 1) & 1]);
        }
        __builtin_amdgcn_sched_barrier(0);   // nothing crosses: reads stay hoisted
        // ---- phase B: consume pair k, store ----
        f2v r;
        r.x = eval_pt(fA[k & 1], va.x, va.y);
        r.y = eval_pt(fB[k & 1], va.z, va.w);
        __builtin_nontemporal_store(r, &out2[tid + k * stride]);
        va = vb;
        vb = vc;
        __builtin_amdgcn_sched_barrier(0);
    }
}

extern "C" void kernel_launch(void* const* d_in, const int* in_sizes, int n_in,
                              void* d_out, int out_size, void* d_ws, size_t ws_size,
                              hipStream_t stream) {
    const float* inputs = (const float*)d_in[0];   // (2048,2048,2) f32
    const float* coe    = (const float*)d_in[1];   // (257,257) f32
    float* out = (float*)d_out;                    // (2048,2048) f32
    int npairs = out_size >> 1;                    // 2,097,152

    (void)hipFuncSetAttribute((const void*)lagrange_kernel,
                              hipFuncAttributeMaxDynamicSharedMemorySize,
                              LDS_BYTES);

    dim3 grid(GRID), block(BLOCK);   // 1 block/CU (LDS-limited), 16 waves/CU
    hipLaunchKernelGGL(lagrange_kernel, grid, block, LDS_BYTES, stream,
                       inputs, coe, out, npairs);
}